// Round 6
// baseline (82.515 us; speedup 1.0000x reference)
//
#include <hip/hip_runtime.h>

// Problem constants (B=4, C=4, H=64, W=64, K=8192)
static constexpr int TOKENS = 16384;   // B*H*W
static constexpr int HW     = 4096;    // H*W
static constexpr int NSG    = 64;      // codebook slice-groups
static constexpr int ESG    = 128;     // entries per slice-group (NSG*ESG == 8192)
static constexpr int NGROUP = 16;      // token groups
static constexpr int GTOK   = 1024;    // tokens per group (NGROUP*GTOK == TOKENS)
static constexpr int TPT    = 4;       // tokens per thread

// ---------------------------------------------------------------------------
// Kernel 0: init packed-argmin array + control words (harness does not
// re-poison between replays, so this must run every call).
// ---------------------------------------------------------------------------
__global__ __launch_bounds__(256) void k_init(
    unsigned long long* __restrict__ A,
    float* __restrict__ acc, unsigned* __restrict__ done,
    unsigned* __restrict__ gcnt)
{
    int i = blockIdx.x * 256 + threadIdx.x;
    A[i] = 0xFFFFFFFFFFFFFFFFull;   // > any real key (high word <= ~0xFF80xxxx)
    if (blockIdx.x == 0) {
        if (threadIdx.x < NGROUP) gcnt[threadIdx.x] = 0u;
        if (threadIdx.x == NGROUP) { *acc = 0.0f; *done = 0u; }
    }
}

// ---------------------------------------------------------------------------
// Kernel 1: FULLY FUSED conv + sliced argmin (atomicMin) + per-group output
// + loss. 1024 blocks = 64 slice-groups x 16 token groups (4 blocks/CU).
// The 64th slice-block to finish a token group becomes that group's consumer
// (it already holds the group's conv results in registers: x = -0.5*m).
// ---------------------------------------------------------------------------
__global__ __launch_bounds__(256, 4) void k_fused(
    const float* __restrict__ z,      // [B,C,H,W]
    const float* __restrict__ w,      // [4,4]
    const float* __restrict__ bias,   // [4]
    const float4* __restrict__ CB,    // [8192]
    unsigned long long* __restrict__ A,
    float* __restrict__ out,          // [B,C,H,W] (+ loss at [TOKENS*4])
    float* __restrict__ acc, unsigned* __restrict__ done,
    unsigned* __restrict__ gcnt)
{
    const int bx  = blockIdx.x;
    const int g   = bx & (NGROUP - 1);
    const int s   = bx >> 4;          // NGROUP == 16
    const int tid = threadIdx.x;

    // ---- 1x1 conv for this group's tokens (w/bias uniform -> s_loads) ----
    const int tbase = g * GTOK + tid;
    float m0[TPT], m1[TPT], m2[TPT], m3[TPT], bv[TPT], x2s[TPT];
    int bi[TPT];
#pragma unroll
    for (int j = 0; j < TPT; ++j) {
        int t = tbase + j * 256;
        int b = t >> 12;
        int n = t & (HW - 1);
        const float* zb = z + b * (4 * HW) + n;
        float z0 = zb[0], z1 = zb[HW], z2 = zb[2 * HW], z3 = zb[3 * HW];
        float x0 = fmaf(w[3],  z3, fmaf(w[2],  z2, fmaf(w[1],  z1, fmaf(w[0],  z0, bias[0]))));
        float x1 = fmaf(w[7],  z3, fmaf(w[6],  z2, fmaf(w[5],  z1, fmaf(w[4],  z0, bias[1]))));
        float x2 = fmaf(w[11], z3, fmaf(w[10], z2, fmaf(w[9],  z1, fmaf(w[8],  z0, bias[2]))));
        float x3 = fmaf(w[15], z3, fmaf(w[14], z2, fmaf(w[13], z1, fmaf(w[12], z0, bias[3]))));
        m0[j] = -2.0f * x0;
        m1[j] = -2.0f * x1;
        m2[j] = -2.0f * x2;
        m3[j] = -2.0f * x3;
        x2s[j] = fmaf(x3, x3, fmaf(x2, x2, fmaf(x1, x1, x0 * x0)));
        bv[j] = 3.0e38f;
        bi[j] = 0;
    }

    // ---- sliced distance scan: wave-uniform scalar loads, pure-VALU loop ----
    const int sbase = __builtin_amdgcn_readfirstlane(s * ESG);
    const float4* __restrict__ cs = CB + sbase;
#pragma unroll 8
    for (int e = 0; e < ESG; ++e) {
        float4 c = cs[e];             // uniform address -> scalar pipe
        float cn = fmaf(c.w, c.w, fmaf(c.z, c.z, fmaf(c.y, c.y, c.x * c.x)));
#pragma unroll
        for (int j = 0; j < TPT; ++j) {
            float d = fmaf(m0[j], c.x, fmaf(m1[j], c.y, fmaf(m2[j], c.z, fmaf(m3[j], c.w, cn))));
            bool lt = d < bv[j];      // strict < keeps lowest idx in-range
            bv[j] = lt ? d : bv[j];
            bi[j] = lt ? e : bi[j];
        }
    }

    // ---- publish (distance, index) as sortable 64-bit key ----
#pragma unroll
    for (int j = 0; j < TPT; ++j) {
        float D = bv[j] + x2s[j];     // full |x-c|^2 (may round slightly negative)
        unsigned u = __float_as_uint(D);
        u ^= (unsigned)((int)u >> 31) | 0x80000000u;   // monotone float->uint
        unsigned long long key =
            ((unsigned long long)u << 32) | (unsigned)(sbase + bi[j]);
        atomicMin(&A[tbase + j * 256], key);
    }

    // ---- last slice-block for this token group becomes its consumer ----
    __threadfence();
    __shared__ int lastflag;
    if (tid == 0) lastflag = (atomicAdd(&gcnt[g], 1u) == NSG - 1);
    __syncthreads();
    if (!lastflag) return;

    float ls = 0.0f;
#pragma unroll
    for (int j = 0; j < TPT; ++j) {
        int t = tbase + j * 256;
        unsigned long long key = atomicAdd(&A[t], 0ull);  // coherent (L2) read
        int idx = (int)(key & 8191u);
        float4 qv = CB[idx];
        float x0 = -0.5f * m0[j];     // exact recovery of x from m = -2x
        float x1 = -0.5f * m1[j];
        float x2 = -0.5f * m2[j];
        float x3 = -0.5f * m3[j];
        float d0 = qv.x - x0, d1 = qv.y - x1, d2 = qv.z - x2, d3 = qv.w - x3;
        int b = t >> 12;
        int n = t & (HW - 1);
        float* ob = out + b * (4 * HW) + n;
        ob[0]      = x0 + d0;         // straight-through: x + (q - x)
        ob[HW]     = x1 + d1;
        ob[2 * HW] = x2 + d2;
        ob[3 * HW] = x3 + d3;
        ls += fmaf(d3, d3, fmaf(d2, d2, fmaf(d1, d1, d0 * d0)));
    }

#pragma unroll
    for (int off = 32; off > 0; off >>= 1)
        ls += __shfl_down(ls, off, 64);
    __shared__ float wsum[4];
    if ((tid & 63) == 0) wsum[tid >> 6] = ls;
    __syncthreads();
    if (tid == 0) {
        atomicAdd(acc, wsum[0] + wsum[1] + wsum[2] + wsum[3]);
        __threadfence();
        if (atomicAdd(done, 1u) == NGROUP - 1) {
            float m = atomicAdd(acc, 0.0f) * (1.0f / 65536.0f);  // mean over B*N*C
            out[TOKENS * 4] = m + 0.25f * m;   // codebook_loss + BETA*commitment
        }
    }
}

extern "C" void kernel_launch(void* const* d_in, const int* in_sizes, int n_in,
                              void* d_out, int out_size, void* d_ws, size_t ws_size,
                              hipStream_t stream)
{
    const float* z    = (const float*)d_in[0];
    const float* w    = (const float*)d_in[1];
    const float* bias = (const float*)d_in[2];
    const float* cb   = (const float*)d_in[3];
    float* out = (float*)d_out;

    char* ws = (char*)d_ws;
    float*              acc  = (float*)ws;                       // 4 B
    unsigned*           done = (unsigned*)(ws + 64);             // 4 B
    unsigned*           gcnt = (unsigned*)(ws + 128);            // 64 B
    unsigned long long* A    = (unsigned long long*)(ws + 1024); // 128 KiB

    const float4* CB4 = (const float4*)cb;

    k_init<<<TOKENS / 256, 256, 0, stream>>>(A, acc, done, gcnt);
    k_fused<<<NSG * NGROUP, 256, 0, stream>>>(z, w, bias, CB4, A, out, acc, done, gcnt);
}

// Round 7
// 45.598 us; speedup vs baseline: 1.8096x; 1.8096x over previous
//
#include <hip/hip_runtime.h>

// Problem constants (B=4, C=4, H=64, W=64, K=8192)
static constexpr int TOKENS = 16384;   // B*H*W
static constexpr int HW     = 4096;    // H*W
static constexpr int NSG    = 64;      // codebook slice-groups
static constexpr int ESG    = 128;     // entries per slice-group (NSG*ESG == 8192)
static constexpr int NGROUP = 16;      // token groups
static constexpr int GTOK   = 1024;    // tokens per group (NGROUP*GTOK == TOKENS)
static constexpr int TPT    = 4;       // tokens per thread

// ---------------------------------------------------------------------------
// Kernel 1: fused pre-quant conv + sliced distance argmin -> P array.
// 1024 blocks = 64 slice-groups x 16 token groups (4 blocks/CU).
// Codebook via wave-uniform scalar loads; inner loop pure VALU (8 inst/pair).
// No atomics, no fences: each P slot is written by exactly one thread.
// ---------------------------------------------------------------------------
__global__ __launch_bounds__(256, 4) void k_dist(
    const float* __restrict__ z,      // [B,C,H,W]
    const float* __restrict__ w,      // [4,4]
    const float* __restrict__ bias,   // [4]
    const float4* __restrict__ CB,    // [8192]
    float2* __restrict__ P,           // [NSG*TOKENS] (dist, idx bits)
    float* __restrict__ acc, unsigned* __restrict__ done)
{
    const int bx  = blockIdx.x;
    const int g   = bx & (NGROUP - 1);
    const int s   = bx >> 4;          // NGROUP == 16
    const int tid = threadIdx.x;
    if (bx == 0 && tid == 0) { *acc = 0.0f; *done = 0u; }  // consumed only by k_out

    // ---- 1x1 conv for this thread's tokens (w/bias uniform -> s_loads) ----
    const int tbase = g * GTOK + tid;
    float m0[TPT], m1[TPT], m2[TPT], m3[TPT], bv[TPT], x2s[TPT];
    int bi[TPT];
#pragma unroll
    for (int j = 0; j < TPT; ++j) {
        int t = tbase + j * 256;
        int b = t >> 12;
        int n = t & (HW - 1);
        const float* zb = z + b * (4 * HW) + n;
        float z0 = zb[0], z1 = zb[HW], z2 = zb[2 * HW], z3 = zb[3 * HW];
        float x0 = fmaf(w[3],  z3, fmaf(w[2],  z2, fmaf(w[1],  z1, fmaf(w[0],  z0, bias[0]))));
        float x1 = fmaf(w[7],  z3, fmaf(w[6],  z2, fmaf(w[5],  z1, fmaf(w[4],  z0, bias[1]))));
        float x2 = fmaf(w[11], z3, fmaf(w[10], z2, fmaf(w[9],  z1, fmaf(w[8],  z0, bias[2]))));
        float x3 = fmaf(w[15], z3, fmaf(w[14], z2, fmaf(w[13], z1, fmaf(w[12], z0, bias[3]))));
        m0[j] = -2.0f * x0;
        m1[j] = -2.0f * x1;
        m2[j] = -2.0f * x2;
        m3[j] = -2.0f * x3;
        x2s[j] = fmaf(x3, x3, fmaf(x2, x2, fmaf(x1, x1, x0 * x0)));
        bv[j] = 3.0e38f;
        bi[j] = 0;
    }

    // ---- sliced distance scan: wave-uniform scalar loads, pure-VALU loop ----
    const int sbase = __builtin_amdgcn_readfirstlane(s * ESG);
    const float4* __restrict__ cs = CB + sbase;
#pragma unroll 8
    for (int e = 0; e < ESG; ++e) {
        float4 c = cs[e];             // uniform address -> scalar (SMEM) pipe
        float cn = fmaf(c.w, c.w, fmaf(c.z, c.z, fmaf(c.y, c.y, c.x * c.x)));
#pragma unroll
        for (int j = 0; j < TPT; ++j) {
            float d = fmaf(m0[j], c.x, fmaf(m1[j], c.y, fmaf(m2[j], c.z, fmaf(m3[j], c.w, cn))));
            bool lt = d < bv[j];      // strict < keeps lowest idx in-range
            bv[j] = lt ? d : bv[j];
            bi[j] = lt ? e : bi[j];
        }
    }

    // ---- plain coalesced stores (one writer per slot, no atomics) ----
#pragma unroll
    for (int j = 0; j < TPT; ++j) {
        int t = tbase + j * 256;
        float D = bv[j] + x2s[j];     // full |x-c|^2 for cross-slice compare
        P[s * TOKENS + t] = make_float2(D, __int_as_float(sbase + bi[j]));
    }
}

// ---------------------------------------------------------------------------
// Kernel 2: reduce 64 slice-partials (4 threads/token) + gather + output +
// loss (last-block finalize). 256 blocks x 256 threads.
// ---------------------------------------------------------------------------
__global__ __launch_bounds__(256) void k_out(
    const float* __restrict__ z,
    const float* __restrict__ w,
    const float* __restrict__ bias,
    const float4* __restrict__ CB,
    const float2* __restrict__ P,
    float* __restrict__ out,          // [B,C,H,W] (+ loss at [TOKENS*4])
    float* __restrict__ acc, unsigned* __restrict__ done)
{
    int G = blockIdx.x * 256 + threadIdx.x;   // 0..65535
    int t = G >> 2;                           // token
    int q = G & 3;                            // slice-quarter

    float bv = 3.0e38f;
    int bi = 0;
#pragma unroll 4
    for (int i = 0; i < 16; ++i) {
        float2 p = P[(q * 16 + i) * TOKENS + t];
        if (p.x < bv) { bv = p.x; bi = __float_as_int(p.y); }  // ascending -> lowest idx
    }
    // combine the 4 quarters; tie -> lowest global index (matches argmin)
#pragma unroll
    for (int m = 1; m <= 2; m <<= 1) {
        float ov = __shfl_xor(bv, m, 64);
        int   oi = __shfl_xor(bi, m, 64);
        if (ov < bv || (ov == bv && oi < bi)) { bv = ov; bi = oi; }
    }

    int b = t >> 12;
    int n = t & (HW - 1);
    const float* zb = z + b * (4 * HW) + n;
    float z0 = zb[0], z1 = zb[HW], z2 = zb[2 * HW], z3 = zb[3 * HW];
    float x0 = fmaf(w[3],  z3, fmaf(w[2],  z2, fmaf(w[1],  z1, fmaf(w[0],  z0, bias[0]))));
    float x1 = fmaf(w[7],  z3, fmaf(w[6],  z2, fmaf(w[5],  z1, fmaf(w[4],  z0, bias[1]))));
    float x2 = fmaf(w[11], z3, fmaf(w[10], z2, fmaf(w[9],  z1, fmaf(w[8],  z0, bias[2]))));
    float x3 = fmaf(w[15], z3, fmaf(w[14], z2, fmaf(w[13], z1, fmaf(w[12], z0, bias[3]))));

    float4 qv = CB[bi];
    float d0 = qv.x - x0, d1 = qv.y - x1, d2 = qv.z - x2, d3 = qv.w - x3;

    float ls = 0.0f;
    if (q == 0) {
        float* ob = out + b * (4 * HW) + n;
        ob[0]      = x0 + d0;    // straight-through: x + (q - x)
        ob[HW]     = x1 + d1;
        ob[2 * HW] = x2 + d2;
        ob[3 * HW] = x3 + d3;
        ls = fmaf(d3, d3, fmaf(d2, d2, fmaf(d1, d1, d0 * d0)));
    }

#pragma unroll
    for (int off = 32; off > 0; off >>= 1)
        ls += __shfl_down(ls, off, 64);
    __shared__ float wsum[4];
    if ((threadIdx.x & 63) == 0) wsum[threadIdx.x >> 6] = ls;
    __syncthreads();
    if (threadIdx.x == 0) {
        atomicAdd(acc, wsum[0] + wsum[1] + wsum[2] + wsum[3]);
        __threadfence();
        if (atomicAdd(done, 1u) == gridDim.x - 1) {
            float m = atomicAdd(acc, 0.0f) * (1.0f / 65536.0f);  // mean over B*N*C
            out[TOKENS * 4] = m + 0.25f * m;   // codebook_loss + BETA*commitment
        }
    }
}

extern "C" void kernel_launch(void* const* d_in, const int* in_sizes, int n_in,
                              void* d_out, int out_size, void* d_ws, size_t ws_size,
                              hipStream_t stream)
{
    const float* z    = (const float*)d_in[0];
    const float* w    = (const float*)d_in[1];
    const float* bias = (const float*)d_in[2];
    const float* cb   = (const float*)d_in[3];
    float* out = (float*)d_out;

    char* ws = (char*)d_ws;
    float*    acc  = (float*)ws;                 // 4 B
    unsigned* done = (unsigned*)(ws + 64);       // 4 B
    float2*   P    = (float2*)(ws + 1024);       // 8 MiB

    const float4* CB4 = (const float4*)cb;

    k_dist<<<NSG * NGROUP, 256, 0, stream>>>(z, w, bias, CB4, P, acc, done);
    k_out<<<TOKENS * 4 / 256, 256, 0, stream>>>(z, w, bias, CB4, P, out, acc, done);
}

// Round 8
// 44.036 us; speedup vs baseline: 1.8738x; 1.0355x over previous
//
#include <hip/hip_runtime.h>

// Problem constants (B=4, C=4, H=64, W=64, K=8192)
static constexpr int TOKENS = 16384;   // B*H*W
static constexpr int HW     = 4096;    // H*W
static constexpr int NSG    = 32;      // codebook slice-groups
static constexpr int ESG    = 256;     // entries per slice-group (NSG*ESG == 8192)
static constexpr int NGROUP = 32;      // token groups
static constexpr int GTOK   = 512;     // tokens per group (NGROUP*GTOK == TOKENS)
static constexpr int TPT    = 2;       // tokens per thread (GTOK/256)

// ---------------------------------------------------------------------------
// Kernel 0: init packed-argmin array + control words. Must run every call:
// replay 1 sees 0xAA poison in A (0xAAAA.. packs a tiny positive distance,
// which would incorrectly win atomicMin), and the harness never re-poisons.
// ---------------------------------------------------------------------------
__global__ __launch_bounds__(256) void k_init(
    unsigned long long* __restrict__ A,
    float* __restrict__ acc, unsigned* __restrict__ done)
{
    int i = blockIdx.x * 256 + threadIdx.x;   // 64 blocks -> 16384 slots
    A[i] = 0xFFFFFFFFFFFFFFFFull;             // > any real key (hi <= ~0xFF800000)
    if (i == 0) { *acc = 0.0f; *done = 0u; }
}

// ---------------------------------------------------------------------------
// Kernel 1: fused pre-quant conv + sliced distance argmin via atomicMin.
// 1024 blocks = 32 slice-groups x 32 token groups (4 blocks/CU).
// Codebook via wave-uniform scalar (SMEM) loads; inner loop pure VALU
// (9 inst/pair at TPT=2). 512K fire-and-forget atomicMins total (half of R5).
// key = sortable(D) << 32 | idx  ->  min key = min distance, ties -> low idx.
// ---------------------------------------------------------------------------
__global__ __launch_bounds__(256, 4) void k_dist(
    const float* __restrict__ z,      // [B,C,H,W]
    const float* __restrict__ w,      // [4,4]
    const float* __restrict__ bias,   // [4]
    const float4* __restrict__ CB,    // [8192]
    unsigned long long* __restrict__ A)
{
    const int bx  = blockIdx.x;
    const int g   = bx & (NGROUP - 1);
    const int s   = bx >> 5;          // NGROUP == 32
    const int tid = threadIdx.x;

    // ---- 1x1 conv for this thread's tokens (w/bias uniform -> s_loads) ----
    const int tbase = g * GTOK + tid;
    float m0[TPT], m1[TPT], m2[TPT], m3[TPT], bv[TPT], x2s[TPT];
    int bi[TPT];
#pragma unroll
    for (int j = 0; j < TPT; ++j) {
        int t = tbase + j * 256;
        int b = t >> 12;
        int n = t & (HW - 1);
        const float* zb = z + b * (4 * HW) + n;
        float z0 = zb[0], z1 = zb[HW], z2 = zb[2 * HW], z3 = zb[3 * HW];
        float x0 = fmaf(w[3],  z3, fmaf(w[2],  z2, fmaf(w[1],  z1, fmaf(w[0],  z0, bias[0]))));
        float x1 = fmaf(w[7],  z3, fmaf(w[6],  z2, fmaf(w[5],  z1, fmaf(w[4],  z0, bias[1]))));
        float x2 = fmaf(w[11], z3, fmaf(w[10], z2, fmaf(w[9],  z1, fmaf(w[8],  z0, bias[2]))));
        float x3 = fmaf(w[15], z3, fmaf(w[14], z2, fmaf(w[13], z1, fmaf(w[12], z0, bias[3]))));
        m0[j] = -2.0f * x0;
        m1[j] = -2.0f * x1;
        m2[j] = -2.0f * x2;
        m3[j] = -2.0f * x3;
        x2s[j] = fmaf(x3, x3, fmaf(x2, x2, fmaf(x1, x1, x0 * x0)));
        bv[j] = 3.0e38f;
        bi[j] = 0;
    }

    // ---- sliced distance scan: wave-uniform scalar loads, pure-VALU loop ----
    const int sbase = __builtin_amdgcn_readfirstlane(s * ESG);
    const float4* __restrict__ cs = CB + sbase;
#pragma unroll 8
    for (int e = 0; e < ESG; ++e) {
        float4 c = cs[e];             // uniform address -> scalar (SMEM) pipe
        float cn = fmaf(c.w, c.w, fmaf(c.z, c.z, fmaf(c.y, c.y, c.x * c.x)));
#pragma unroll
        for (int j = 0; j < TPT; ++j) {
            float d = fmaf(m0[j], c.x, fmaf(m1[j], c.y, fmaf(m2[j], c.z, fmaf(m3[j], c.w, cn))));
            bool lt = d < bv[j];      // strict < keeps lowest idx in-range
            bv[j] = lt ? d : bv[j];
            bi[j] = lt ? e : bi[j];
        }
    }

    // ---- publish (distance, index) as sortable 64-bit key; no fence ----
#pragma unroll
    for (int j = 0; j < TPT; ++j) {
        float D = bv[j] + x2s[j];     // full |x-c|^2 (may round slightly negative)
        unsigned u = __float_as_uint(D);
        u ^= (unsigned)((int)u >> 31) | 0x80000000u;   // monotone float->uint map
        unsigned long long key =
            ((unsigned long long)u << 32) | (unsigned)(sbase + bi[j]);
        atomicMin(&A[tbase + j * 256], key);
    }
}

// ---------------------------------------------------------------------------
// Kernel 2: unpack argmin + gather + straight-through output + loss.
// 64 blocks x 256 threads, 1 token/thread. A is settled by stream order,
// so a plain load suffices (no atomics/fences on the read path).
// ---------------------------------------------------------------------------
__global__ __launch_bounds__(256) void k_out(
    const float* __restrict__ z,
    const float* __restrict__ w,
    const float* __restrict__ bias,
    const float4* __restrict__ CB,
    const unsigned long long* __restrict__ A,
    float* __restrict__ out,          // [B,C,H,W] (+ loss at [TOKENS*4])
    float* __restrict__ acc, unsigned* __restrict__ done)
{
    int t = blockIdx.x * 256 + threadIdx.x;
    int b = t >> 12;
    int n = t & (HW - 1);

    const float* zb = z + b * (4 * HW) + n;
    float z0 = zb[0], z1 = zb[HW], z2 = zb[2 * HW], z3 = zb[3 * HW];
    float x0 = fmaf(w[3],  z3, fmaf(w[2],  z2, fmaf(w[1],  z1, fmaf(w[0],  z0, bias[0]))));
    float x1 = fmaf(w[7],  z3, fmaf(w[6],  z2, fmaf(w[5],  z1, fmaf(w[4],  z0, bias[1]))));
    float x2 = fmaf(w[11], z3, fmaf(w[10], z2, fmaf(w[9],  z1, fmaf(w[8],  z0, bias[2]))));
    float x3 = fmaf(w[15], z3, fmaf(w[14], z2, fmaf(w[13], z1, fmaf(w[12], z0, bias[3]))));

    int idx = (int)((unsigned)A[t] & 8191u);
    float4 qv = CB[idx];
    float d0 = qv.x - x0, d1 = qv.y - x1, d2 = qv.z - x2, d3 = qv.w - x3;

    float* ob = out + b * (4 * HW) + n;
    ob[0]      = x0 + d0;    // straight-through: x + (q - x)
    ob[HW]     = x1 + d1;
    ob[2 * HW] = x2 + d2;
    ob[3 * HW] = x3 + d3;

    float ls = fmaf(d3, d3, fmaf(d2, d2, fmaf(d1, d1, d0 * d0)));
#pragma unroll
    for (int off = 32; off > 0; off >>= 1)
        ls += __shfl_down(ls, off, 64);
    __shared__ float wsum[4];
    if ((threadIdx.x & 63) == 0) wsum[threadIdx.x >> 6] = ls;
    __syncthreads();
    if (threadIdx.x == 0) {
        atomicAdd(acc, wsum[0] + wsum[1] + wsum[2] + wsum[3]);
        __threadfence();
        if (atomicAdd(done, 1u) == gridDim.x - 1) {
            float m = atomicAdd(acc, 0.0f) * (1.0f / 65536.0f);  // mean over B*N*C
            out[TOKENS * 4] = m + 0.25f * m;   // codebook_loss + BETA*commitment
        }
    }
}

extern "C" void kernel_launch(void* const* d_in, const int* in_sizes, int n_in,
                              void* d_out, int out_size, void* d_ws, size_t ws_size,
                              hipStream_t stream)
{
    const float* z    = (const float*)d_in[0];
    const float* w    = (const float*)d_in[1];
    const float* bias = (const float*)d_in[2];
    const float* cb   = (const float*)d_in[3];
    float* out = (float*)d_out;

    char* ws = (char*)d_ws;
    float*              acc  = (float*)ws;                       // 4 B
    unsigned*           done = (unsigned*)(ws + 64);             // 4 B
    unsigned long long* A    = (unsigned long long*)(ws + 1024); // 128 KiB

    const float4* CB4 = (const float4*)cb;

    k_init<<<TOKENS / 256, 256, 0, stream>>>(A, acc, done);
    k_dist<<<NSG * NGROUP, 256, 0, stream>>>(z, w, bias, CB4, A);
    k_out<<<TOKENS / 256, 256, 0, stream>>>(z, w, bias, CB4, A, out, acc, done);
}

// Round 9
// 38.447 us; speedup vs baseline: 2.1462x; 1.1454x over previous
//
#include <hip/hip_runtime.h>

// Problem constants (B=4, C=4, H=64, W=64, K=8192)
static constexpr int TOKENS = 16384;   // B*H*W
static constexpr int HW     = 4096;    // H*W
static constexpr int NSG    = 64;      // codebook slice-groups
static constexpr int ESG    = 128;     // entries per slice-group (NSG*ESG == 8192)
static constexpr int NGROUP = 8;       // token groups
static constexpr int GTOK   = 2048;    // tokens per group (NGROUP*GTOK == TOKENS)
static constexpr int TPT    = 8;       // tokens per thread (GTOK/256)

// ---------------------------------------------------------------------------
// Kernel 0: init packed-argmin array + control words. Must run every call
// (first replay sees 0xAA poison in A, which would win atomicMin; harness
// never re-poisons between replays).
// ---------------------------------------------------------------------------
__global__ __launch_bounds__(256) void k_init(
    unsigned long long* __restrict__ A,
    float* __restrict__ acc, unsigned* __restrict__ done)
{
    int i = blockIdx.x * 256 + threadIdx.x;   // 64 blocks -> 16384 slots
    A[i] = 0xFFFFFFFFFFFFFFFFull;             // > any real key (hi <= ~0xFF800000)
    if (i == 0) { *acc = 0.0f; *done = 0u; }
}

// ---------------------------------------------------------------------------
// Kernel 1: fused pre-quant conv + sliced distance argmin via atomicMin.
// 512 blocks = 64 slice-groups x 8 token groups (2 blocks/CU).
// Codebook slice (2 KiB) + |c|^2 staged in LDS; inner loop reads are pure
// broadcast (all lanes same address -> conflict-free), hot loop has NO VMEM.
// Per-pair VALU = 4 fma + cmp + 2 sel = 7 (cn amortized 1/8) -> 12.0 us floor.
// key = sortable(D) << 32 | idx  ->  min key = min distance, ties -> low idx.
// ---------------------------------------------------------------------------
__global__ __launch_bounds__(256, 2) void k_dist(
    const float* __restrict__ z,      // [B,C,H,W]
    const float* __restrict__ w,      // [4,4]
    const float* __restrict__ bias,   // [4]
    const float4* __restrict__ CB,    // [8192]
    unsigned long long* __restrict__ A)
{
    __shared__ float4 cbs[ESG];
    __shared__ float  cns[ESG];
    const int bx  = blockIdx.x;
    const int g   = bx & (NGROUP - 1);
    const int s   = bx >> 3;          // NGROUP == 8
    const int tid = threadIdx.x;

    // ---- stage this slice of the codebook + squared norms into LDS ----
    if (tid < ESG) {
        float4 c = CB[s * ESG + tid];
        cbs[tid] = c;
        cns[tid] = fmaf(c.w, c.w, fmaf(c.z, c.z, fmaf(c.y, c.y, c.x * c.x)));
    }

    // ---- 1x1 conv for this thread's 8 tokens (w/bias uniform -> s_loads) ----
    const int tbase = g * GTOK + tid;
    float m0[TPT], m1[TPT], m2[TPT], m3[TPT], bv[TPT], x2s[TPT];
    int bi[TPT];
#pragma unroll
    for (int j = 0; j < TPT; ++j) {
        int t = tbase + j * 256;
        int b = t >> 12;
        int n = t & (HW - 1);
        const float* zb = z + b * (4 * HW) + n;
        float z0 = zb[0], z1 = zb[HW], z2 = zb[2 * HW], z3 = zb[3 * HW];
        float x0 = fmaf(w[3],  z3, fmaf(w[2],  z2, fmaf(w[1],  z1, fmaf(w[0],  z0, bias[0]))));
        float x1 = fmaf(w[7],  z3, fmaf(w[6],  z2, fmaf(w[5],  z1, fmaf(w[4],  z0, bias[1]))));
        float x2 = fmaf(w[11], z3, fmaf(w[10], z2, fmaf(w[9],  z1, fmaf(w[8],  z0, bias[2]))));
        float x3 = fmaf(w[15], z3, fmaf(w[14], z2, fmaf(w[13], z1, fmaf(w[12], z0, bias[3]))));
        m0[j] = -2.0f * x0;
        m1[j] = -2.0f * x1;
        m2[j] = -2.0f * x2;
        m3[j] = -2.0f * x3;
        x2s[j] = fmaf(x3, x3, fmaf(x2, x2, fmaf(x1, x1, x0 * x0)));
        bv[j] = 3.0e38f;
        bi[j] = 0;
    }
    __syncthreads();

    // ---- distance scan: broadcast LDS reads, 8 independent select chains ----
#pragma unroll 4
    for (int e = 0; e < ESG; ++e) {
        float4 c  = cbs[e];           // all lanes same address -> LDS broadcast
        float  cn = cns[e];
#pragma unroll
        for (int j = 0; j < TPT; ++j) {
            float d = fmaf(m0[j], c.x, fmaf(m1[j], c.y, fmaf(m2[j], c.z, fmaf(m3[j], c.w, cn))));
            bool lt = d < bv[j];      // strict < keeps lowest idx in-range
            bv[j] = lt ? d : bv[j];
            bi[j] = lt ? e : bi[j];
        }
    }

    // ---- publish (distance, index) as sortable 64-bit key; no fence ----
    const int sbase = s * ESG;
#pragma unroll
    for (int j = 0; j < TPT; ++j) {
        float D = bv[j] + x2s[j];     // full |x-c|^2 (may round slightly negative)
        unsigned u = __float_as_uint(D);
        u ^= (unsigned)((int)u >> 31) | 0x80000000u;   // monotone float->uint map
        unsigned long long key =
            ((unsigned long long)u << 32) | (unsigned)(sbase + bi[j]);
        atomicMin(&A[tbase + j * 256], key);
    }
}

// ---------------------------------------------------------------------------
// Kernel 2: unpack argmin + gather + straight-through output + loss.
// 64 blocks x 256 threads, 1 token/thread. A is settled by stream order.
// ---------------------------------------------------------------------------
__global__ __launch_bounds__(256) void k_out(
    const float* __restrict__ z,
    const float* __restrict__ w,
    const float* __restrict__ bias,
    const float4* __restrict__ CB,
    const unsigned long long* __restrict__ A,
    float* __restrict__ out,          // [B,C,H,W] (+ loss at [TOKENS*4])
    float* __restrict__ acc, unsigned* __restrict__ done)
{
    int t = blockIdx.x * 256 + threadIdx.x;
    int b = t >> 12;
    int n = t & (HW - 1);

    const float* zb = z + b * (4 * HW) + n;
    float z0 = zb[0], z1 = zb[HW], z2 = zb[2 * HW], z3 = zb[3 * HW];
    float x0 = fmaf(w[3],  z3, fmaf(w[2],  z2, fmaf(w[1],  z1, fmaf(w[0],  z0, bias[0]))));
    float x1 = fmaf(w[7],  z3, fmaf(w[6],  z2, fmaf(w[5],  z1, fmaf(w[4],  z0, bias[1]))));
    float x2 = fmaf(w[11], z3, fmaf(w[10], z2, fmaf(w[9],  z1, fmaf(w[8],  z0, bias[2]))));
    float x3 = fmaf(w[15], z3, fmaf(w[14], z2, fmaf(w[13], z1, fmaf(w[12], z0, bias[3]))));

    int idx = (int)((unsigned)A[t] & 8191u);
    float4 qv = CB[idx];
    float d0 = qv.x - x0, d1 = qv.y - x1, d2 = qv.z - x2, d3 = qv.w - x3;

    float* ob = out + b * (4 * HW) + n;
    ob[0]      = x0 + d0;    // straight-through: x + (q - x)
    ob[HW]     = x1 + d1;
    ob[2 * HW] = x2 + d2;
    ob[3 * HW] = x3 + d3;

    float ls = fmaf(d3, d3, fmaf(d2, d2, fmaf(d1, d1, d0 * d0)));
#pragma unroll
    for (int off = 32; off > 0; off >>= 1)
        ls += __shfl_down(ls, off, 64);
    __shared__ float wsum[4];
    if ((threadIdx.x & 63) == 0) wsum[threadIdx.x >> 6] = ls;
    __syncthreads();
    if (threadIdx.x == 0) {
        atomicAdd(acc, wsum[0] + wsum[1] + wsum[2] + wsum[3]);
        __threadfence();
        if (atomicAdd(done, 1u) == gridDim.x - 1) {
            float m = atomicAdd(acc, 0.0f) * (1.0f / 65536.0f);  // mean over B*N*C
            out[TOKENS * 4] = m + 0.25f * m;   // codebook_loss + BETA*commitment
        }
    }
}

extern "C" void kernel_launch(void* const* d_in, const int* in_sizes, int n_in,
                              void* d_out, int out_size, void* d_ws, size_t ws_size,
                              hipStream_t stream)
{
    const float* z    = (const float*)d_in[0];
    const float* w    = (const float*)d_in[1];
    const float* bias = (const float*)d_in[2];
    const float* cb   = (const float*)d_in[3];
    float* out = (float*)d_out;

    char* ws = (char*)d_ws;
    float*              acc  = (float*)ws;                       // 4 B
    unsigned*           done = (unsigned*)(ws + 64);             // 4 B
    unsigned long long* A    = (unsigned long long*)(ws + 1024); // 128 KiB

    const float4* CB4 = (const float4*)cb;

    k_init<<<TOKENS / 256, 256, 0, stream>>>(A, acc, done);
    k_dist<<<NSG * NGROUP, 256, 0, stream>>>(z, w, bias, CB4, A);
    k_out<<<TOKENS / 256, 256, 0, stream>>>(z, w, bias, CB4, A, out, acc, done);
}

// Round 10
// 38.070 us; speedup vs baseline: 2.1674x; 1.0099x over previous
//
#include <hip/hip_runtime.h>

// Problem constants (B=4, C=4, H=64, W=64, K=8192)
static constexpr int TOKENS = 16384;   // B*H*W
static constexpr int HW     = 4096;    // H*W
static constexpr int NSG    = 64;      // codebook slice-groups
static constexpr int ESG    = 128;     // entries per slice-group (NSG*ESG == 8192)
static constexpr int NGROUP = 8;       // token groups
static constexpr int GTOK   = 2048;    // tokens per group (NGROUP*GTOK == TOKENS)
static constexpr int BT     = 512;     // threads per dist block (8 waves)
static constexpr int TPT    = 4;       // tokens per thread (GTOK/BT)

// ---------------------------------------------------------------------------
// Kernel 0: init packed-argmin array + control words. Must run every call
// (first replay sees 0xAA poison in A, which would win atomicMin; harness
// never re-poisons between replays).
// ---------------------------------------------------------------------------
__global__ __launch_bounds__(256) void k_init(
    unsigned long long* __restrict__ A,
    float* __restrict__ acc, unsigned* __restrict__ done)
{
    int i = blockIdx.x * 256 + threadIdx.x;   // 64 blocks -> 16384 slots
    A[i] = 0xFFFFFFFFFFFFFFFFull;             // > any real key (hi <= ~0xFF800000)
    if (i == 0) { *acc = 0.0f; *done = 0u; }
}

// ---------------------------------------------------------------------------
// Kernel 1: fused pre-quant conv + sliced distance argmin via atomicMin.
// 512 blocks x 512 threads = 64 slice-groups x 8 token groups
// -> 2 blocks/CU = 16 waves/CU = 4 waves/SIMD (2x R9's latency hiding).
// Codebook slice (2.5 KiB incl. |c|^2) staged in LDS; inner-loop reads are
// pure broadcast (all lanes same address, conflict-free); hot loop has no VMEM.
// Key ranks s = |c|^2 - 2 x.c  (per-token monotone in true distance; same
// tie structure since the |x|^2 offset is constant per token).
// key = sortable(s) << 32 | idx  ->  min key = min dist, ties -> lowest idx.
// ---------------------------------------------------------------------------
__global__ __launch_bounds__(BT, 4) void k_dist(
    const float* __restrict__ z,      // [B,C,H,W]
    const float* __restrict__ w,      // [4,4]
    const float* __restrict__ bias,   // [4]
    const float4* __restrict__ CB,    // [8192]
    unsigned long long* __restrict__ A)
{
    __shared__ float4 cbs[ESG];
    __shared__ float  cns[ESG];
    const int bx  = blockIdx.x;
    const int g   = bx & (NGROUP - 1);
    const int s   = bx >> 3;          // NGROUP == 8
    const int tid = threadIdx.x;

    // ---- stage this slice of the codebook + squared norms into LDS ----
    if (tid < ESG) {
        float4 c = CB[s * ESG + tid];
        cbs[tid] = c;
        cns[tid] = fmaf(c.w, c.w, fmaf(c.z, c.z, fmaf(c.y, c.y, c.x * c.x)));
    }

    // ---- 1x1 conv for this thread's tokens (w/bias uniform -> s_loads) ----
    const int tbase = g * GTOK + tid;
    float m0[TPT], m1[TPT], m2[TPT], m3[TPT], bv[TPT];
    int bi[TPT];
#pragma unroll
    for (int j = 0; j < TPT; ++j) {
        int t = tbase + j * BT;
        int b = t >> 12;
        int n = t & (HW - 1);
        const float* zb = z + b * (4 * HW) + n;
        float z0 = zb[0], z1 = zb[HW], z2 = zb[2 * HW], z3 = zb[3 * HW];
        float x0 = fmaf(w[3],  z3, fmaf(w[2],  z2, fmaf(w[1],  z1, fmaf(w[0],  z0, bias[0]))));
        float x1 = fmaf(w[7],  z3, fmaf(w[6],  z2, fmaf(w[5],  z1, fmaf(w[4],  z0, bias[1]))));
        float x2 = fmaf(w[11], z3, fmaf(w[10], z2, fmaf(w[9],  z1, fmaf(w[8],  z0, bias[2]))));
        float x3 = fmaf(w[15], z3, fmaf(w[14], z2, fmaf(w[13], z1, fmaf(w[12], z0, bias[3]))));
        m0[j] = -2.0f * x0;
        m1[j] = -2.0f * x1;
        m2[j] = -2.0f * x2;
        m3[j] = -2.0f * x3;
        bv[j] = 3.0e38f;
        bi[j] = 0;
    }
    __syncthreads();

    // ---- distance scan: broadcast LDS reads, TPT independent select chains ----
#pragma unroll 4
    for (int e = 0; e < ESG; ++e) {
        float4 c  = cbs[e];           // all lanes same address -> LDS broadcast
        float  cn = cns[e];
#pragma unroll
        for (int j = 0; j < TPT; ++j) {
            float d = fmaf(m0[j], c.x, fmaf(m1[j], c.y, fmaf(m2[j], c.z, fmaf(m3[j], c.w, cn))));
            bool lt = d < bv[j];      // strict < keeps lowest idx in-range
            bv[j] = lt ? d : bv[j];
            bi[j] = lt ? e : bi[j];
        }
    }

    // ---- publish (score, index) as sortable 64-bit key; no fence needed ----
    const int sbase = s * ESG;
#pragma unroll
    for (int j = 0; j < TPT; ++j) {
        unsigned u = __float_as_uint(bv[j]);           // s may be negative
        u ^= (unsigned)((int)u >> 31) | 0x80000000u;   // monotone float->uint map
        unsigned long long key =
            ((unsigned long long)u << 32) | (unsigned)(sbase + bi[j]);
        atomicMin(&A[tbase + j * BT], key);
    }
}

// ---------------------------------------------------------------------------
// Kernel 2: unpack argmin + gather + straight-through output + loss.
// 64 blocks x 256 threads, 1 token/thread. A is settled by stream order.
// ---------------------------------------------------------------------------
__global__ __launch_bounds__(256) void k_out(
    const float* __restrict__ z,
    const float* __restrict__ w,
    const float* __restrict__ bias,
    const float4* __restrict__ CB,
    const unsigned long long* __restrict__ A,
    float* __restrict__ out,          // [B,C,H,W] (+ loss at [TOKENS*4])
    float* __restrict__ acc, unsigned* __restrict__ done)
{
    int t = blockIdx.x * 256 + threadIdx.x;
    int b = t >> 12;
    int n = t & (HW - 1);

    const float* zb = z + b * (4 * HW) + n;
    float z0 = zb[0], z1 = zb[HW], z2 = zb[2 * HW], z3 = zb[3 * HW];
    float x0 = fmaf(w[3],  z3, fmaf(w[2],  z2, fmaf(w[1],  z1, fmaf(w[0],  z0, bias[0]))));
    float x1 = fmaf(w[7],  z3, fmaf(w[6],  z2, fmaf(w[5],  z1, fmaf(w[4],  z0, bias[1]))));
    float x2 = fmaf(w[11], z3, fmaf(w[10], z2, fmaf(w[9],  z1, fmaf(w[8],  z0, bias[2]))));
    float x3 = fmaf(w[15], z3, fmaf(w[14], z2, fmaf(w[13], z1, fmaf(w[12], z0, bias[3]))));

    int idx = (int)((unsigned)A[t] & 8191u);
    float4 qv = CB[idx];
    float d0 = qv.x - x0, d1 = qv.y - x1, d2 = qv.z - x2, d3 = qv.w - x3;

    float* ob = out + b * (4 * HW) + n;
    ob[0]      = x0 + d0;    // straight-through: x + (q - x)
    ob[HW]     = x1 + d1;
    ob[2 * HW] = x2 + d2;
    ob[3 * HW] = x3 + d3;

    float ls = fmaf(d3, d3, fmaf(d2, d2, fmaf(d1, d1, d0 * d0)));
#pragma unroll
    for (int off = 32; off > 0; off >>= 1)
        ls += __shfl_down(ls, off, 64);
    __shared__ float wsum[4];
    if ((threadIdx.x & 63) == 0) wsum[threadIdx.x >> 6] = ls;
    __syncthreads();
    if (threadIdx.x == 0) {
        atomicAdd(acc, wsum[0] + wsum[1] + wsum[2] + wsum[3]);
        __threadfence();
        if (atomicAdd(done, 1u) == gridDim.x - 1) {
            float m = atomicAdd(acc, 0.0f) * (1.0f / 65536.0f);  // mean over B*N*C
            out[TOKENS * 4] = m + 0.25f * m;   // codebook_loss + BETA*commitment
        }
    }
}

extern "C" void kernel_launch(void* const* d_in, const int* in_sizes, int n_in,
                              void* d_out, int out_size, void* d_ws, size_t ws_size,
                              hipStream_t stream)
{
    const float* z    = (const float*)d_in[0];
    const float* w    = (const float*)d_in[1];
    const float* bias = (const float*)d_in[2];
    const float* cb   = (const float*)d_in[3];
    float* out = (float*)d_out;

    char* ws = (char*)d_ws;
    float*              acc  = (float*)ws;                       // 4 B
    unsigned*           done = (unsigned*)(ws + 64);             // 4 B
    unsigned long long* A    = (unsigned long long*)(ws + 1024); // 128 KiB

    const float4* CB4 = (const float4*)cb;

    k_init<<<TOKENS / 256, 256, 0, stream>>>(A, acc, done);
    k_dist<<<NSG * NGROUP, BT, 0, stream>>>(z, w, bias, CB4, A);
    k_out<<<TOKENS / 256, 256, 0, stream>>>(z, w, bias, CB4, A, out, acc, done);
}